// Round 2
// baseline (5019.743 us; speedup 1.0000x reference)
//
#include <hip/hip_runtime.h>
#include <cmath>

typedef __bf16 bf16_t;
typedef bf16_t bf16x8 __attribute__((ext_vector_type(8)));
typedef bf16_t bf16x4 __attribute__((ext_vector_type(4)));
typedef float floatx4 __attribute__((ext_vector_type(4)));

#define B_ 2
#define T_ 1024
#define D_ 1024
#define H_ 16
#define DH_ 64
#define L_ 6
#define F_ 4096
#define V_ 32000
#define NTOK (B_ * T_)  // 2048

// ---------------------------------------------------------------- dtype detect
// Samples tok_emb as raw uint16. True-bf16 0.02-scale weights never have
// exponent-field >= 134 (|x| >= 128). fp32 data's low halves are ~uniform
// 16-bit patterns -> ~48% outliers. flag=1 -> inputs are fp32.
__global__ __launch_bounds__(256) void detect_kernel(
    const unsigned short* __restrict__ tok, int* __restrict__ flag)
{
  __shared__ int cnt;
  if (threadIdx.x == 0) cnt = 0;
  __syncthreads();
  int c = 0;
#pragma unroll
  for (int i = 0; i < 16; i++) {
    unsigned short h = tok[threadIdx.x * 16 + i];
    int e = (h >> 7) & 0xFF;
    if (e >= 134) c++;
  }
  atomicAdd(&cnt, c);
  __syncthreads();
  if (threadIdx.x == 0) *flag = (cnt > 64) ? 1 : 0;
}

// dual-dtype loaders for EXTERNAL float tensors (element indexing)
__device__ inline bf16x8 load8(const void* p, size_t i, int fp32m) {
  bf16x8 r;
  if (fp32m) {
    const float* f = (const float*)p + i;
    float4 v0 = *(const float4*)f;
    float4 v1 = *(const float4*)(f + 4);
    r[0] = (bf16_t)v0.x; r[1] = (bf16_t)v0.y; r[2] = (bf16_t)v0.z; r[3] = (bf16_t)v0.w;
    r[4] = (bf16_t)v1.x; r[5] = (bf16_t)v1.y; r[6] = (bf16_t)v1.z; r[7] = (bf16_t)v1.w;
  } else {
    r = *(const bf16x8*)((const bf16_t*)p + i);
  }
  return r;
}

__device__ inline float loadf(const void* p, size_t i, int fp32m) {
  return fp32m ? ((const float*)p)[i] : (float)((const bf16_t*)p)[i];
}

// ---------------------------------------------------------------- embed
__global__ __launch_bounds__(256) void embed_kernel(
    const int* __restrict__ idx, const void* __restrict__ tok,
    const void* __restrict__ pos, float* __restrict__ x,
    const int* __restrict__ modep)
{
  int fp32m = *modep;
  int row = blockIdx.x;            // b*T + t
  int t = row & (T_ - 1);
  int tokid = idx[row];
  int c = threadIdx.x * 4;
  float tv[4], pv[4];
  if (fp32m) {
    float4 a = *(const float4*)((const float*)tok + (size_t)tokid * D_ + c);
    float4 b = *(const float4*)((const float*)pos + (size_t)t * D_ + c);
    tv[0] = a.x; tv[1] = a.y; tv[2] = a.z; tv[3] = a.w;
    pv[0] = b.x; pv[1] = b.y; pv[2] = b.z; pv[3] = b.w;
  } else {
    bf16x4 a = *(const bf16x4*)((const bf16_t*)tok + (size_t)tokid * D_ + c);
    bf16x4 b = *(const bf16x4*)((const bf16_t*)pos + (size_t)t * D_ + c);
#pragma unroll
    for (int j = 0; j < 4; j++) { tv[j] = (float)a[j]; pv[j] = (float)b[j]; }
  }
  float4 o;
  o.x = tv[0] + pv[0]; o.y = tv[1] + pv[1];
  o.z = tv[2] + pv[2]; o.w = tv[3] + pv[3];
  *(float4*)(x + (size_t)row * D_ + c) = o;
}

// ---------------------------------------------------------------- layernorm
// w/b indexed at ELEMENT offset woff + column (dtype-agnostic)
__global__ __launch_bounds__(256) void ln_kernel(
    const float* __restrict__ x, const void* __restrict__ w,
    const void* __restrict__ bb, bf16_t* __restrict__ out,
    const int* __restrict__ modep, int woff)
{
  int fp32m = *modep;
  int row = blockIdx.x, tid = threadIdx.x;
  int lane = tid & 63, wid = tid >> 6;
  const float* xr = x + (size_t)row * D_;
  float4 xv = ((const float4*)xr)[tid];
  float s = xv.x + xv.y + xv.z + xv.w;
  float sq = xv.x * xv.x + xv.y * xv.y + xv.z * xv.z + xv.w * xv.w;
#pragma unroll
  for (int off = 32; off; off >>= 1) {
    s += __shfl_xor(s, off);
    sq += __shfl_xor(sq, off);
  }
  __shared__ float ss[4], ssq[4];
  if (lane == 0) { ss[wid] = s; ssq[wid] = sq; }
  __syncthreads();
  s = ss[0] + ss[1] + ss[2] + ss[3];
  sq = ssq[0] + ssq[1] + ssq[2] + ssq[3];
  float mean = s * (1.f / D_);
  float var = sq * (1.f / D_) - mean * mean;   // jnp.var: biased
  var = fmaxf(var, 0.f);
  float rstd = rsqrtf(var + 1e-5f);
  int c = tid * 4;
  float xa[4] = {xv.x, xv.y, xv.z, xv.w};
  bf16x4 ov;
#pragma unroll
  for (int j = 0; j < 4; j++) {
    float wj = loadf(w, (size_t)woff + c + j, fp32m);
    float bj = loadf(bb, (size_t)woff + c + j, fp32m);
    ov[j] = (bf16_t)((xa[j] - mean) * rstd * wj + bj);
  }
  *(bf16x4*)(out + (size_t)row * D_ + c) = ov;
}

// ---------------------------------------------------------------- gemm C = A @ W^T (+bias)(+gelu)(+res)
// W indexed at ELEMENT offset woffs + n*K + k; bias at boff + n.
__device__ inline float gelu_f(float v) {
  return 0.5f * v * (1.f + erff(v * 0.70710678118654752f));
}

__global__ __launch_bounds__(256) void gemm_bt(
    const bf16_t* __restrict__ A, const void* __restrict__ W, size_t woffs,
    const void* __restrict__ bias, size_t boff, const float* __restrict__ res,
    bf16_t* __restrict__ outb, float* __restrict__ outf, void* __restrict__ outx,
    const int* __restrict__ modep, int M, int N, int K, int dogelu)
{
  __shared__ __align__(16) bf16_t As[64][40];  // +8 pad: 2-way bank alias = free
  __shared__ __align__(16) bf16_t Bs[64][40];
  int fp32m = *modep;
  int tid = threadIdx.x;
  int lane = tid & 63, wid = tid >> 6;
  int wm = wid & 1, wn = wid >> 1;
  int m0 = blockIdx.y * 64, n0 = blockIdx.x * 64;
  int srow = tid >> 2, scol = (tid & 3) * 8;
  const bf16_t* Ap = A + (size_t)(m0 + srow) * K + scol;
  size_t wrow = woffs + (size_t)(n0 + srow) * K + scol;
  floatx4 acc[2][2] = {};
  int ln15 = lane & 15, q4 = lane >> 4;
  for (int k0 = 0; k0 < K; k0 += 32) {
    __syncthreads();
    *(bf16x8*)&As[srow][scol] = *(const bf16x8*)(Ap + k0);
    *(bf16x8*)&Bs[srow][scol] = load8(W, wrow + k0, fp32m);
    __syncthreads();
    bf16x8 a0 = *(const bf16x8*)&As[wm * 32 + ln15][q4 * 8];
    bf16x8 a1 = *(const bf16x8*)&As[wm * 32 + 16 + ln15][q4 * 8];
    bf16x8 b0 = *(const bf16x8*)&Bs[wn * 32 + ln15][q4 * 8];
    bf16x8 b1 = *(const bf16x8*)&Bs[wn * 32 + 16 + ln15][q4 * 8];
    acc[0][0] = __builtin_amdgcn_mfma_f32_16x16x32_bf16(a0, b0, acc[0][0], 0, 0, 0);
    acc[0][1] = __builtin_amdgcn_mfma_f32_16x16x32_bf16(a0, b1, acc[0][1], 0, 0, 0);
    acc[1][0] = __builtin_amdgcn_mfma_f32_16x16x32_bf16(a1, b0, acc[1][0], 0, 0, 0);
    acc[1][1] = __builtin_amdgcn_mfma_f32_16x16x32_bf16(a1, b1, acc[1][1], 0, 0, 0);
  }
#pragma unroll
  for (int mt = 0; mt < 2; mt++)
#pragma unroll
    for (int nt = 0; nt < 2; nt++) {
      int col = n0 + wn * 32 + nt * 16 + ln15;
      float bv = bias ? loadf(bias, boff + col, fp32m) : 0.f;
#pragma unroll
      for (int r = 0; r < 4; r++) {
        int row = m0 + wm * 32 + mt * 16 + q4 * 4 + r;
        float v = acc[mt][nt][r] + bv;
        if (dogelu) v = gelu_f(v);
        size_t o = (size_t)row * N + col;
        if (res) v += res[o];
        if (outf) outf[o] = v;
        if (outb) outb[o] = (bf16_t)v;
        if (outx) {
          if (fp32m) ((float*)outx)[o] = v;
          else ((bf16_t*)outx)[o] = (bf16_t)v;
        }
      }
    }
}

// ---------------------------------------------------------------- flash attention (muP 1/DH scale)
__global__ __launch_bounds__(256) void attn_kernel(
    const bf16_t* __restrict__ q, const bf16_t* __restrict__ k,
    const bf16_t* __restrict__ v, bf16_t* __restrict__ y)
{
  __shared__ float Kt[64][65];
  __shared__ float Vt[64][65];
  __shared__ float qs[4][64];
  __shared__ float ps[4][64];
  int tid = threadIdx.x;
  int lane = tid & 63, w = tid >> 6;
  int blk = blockIdx.x;
  int tqblk = blk & 255;
  int bh = blk >> 8;
  int b = bh >> 4, hh = bh & 15;
  int tq_base = tqblk * 4;
  int tq = tq_base + w;
  size_t rowbase = ((size_t)(b * T_ + tq)) * D_ + hh * DH_;
  qs[w][lane] = (float)q[rowbase + lane];
  float m_i = -INFINITY, l_i = 0.f, acc = 0.f;
  int ntiles = (tq_base >> 6) + 1;
  int lr = tid >> 2, lc = (tid & 3) * 16;
  for (int it = 0; it < ntiles; it++) {
    int tk0 = it * 64;
    __syncthreads();
    size_t gbase = ((size_t)(b * T_ + tk0 + lr)) * D_ + hh * DH_ + lc;
    bf16x8 kv0 = *(const bf16x8*)(k + gbase);
    bf16x8 kv1 = *(const bf16x8*)(k + gbase + 8);
    bf16x8 vv0 = *(const bf16x8*)(v + gbase);
    bf16x8 vv1 = *(const bf16x8*)(v + gbase + 8);
#pragma unroll
    for (int j = 0; j < 8; j++) {
      Kt[lr][lc + j] = (float)kv0[j];
      Kt[lr][lc + 8 + j] = (float)kv1[j];
      Vt[lr][lc + j] = (float)vv0[j];
      Vt[lr][lc + 8 + j] = (float)vv1[j];
    }
    __syncthreads();
    int tk = tk0 + lane;
    float s = -INFINITY;
    if (tk <= tq) {
      float a = 0.f;
#pragma unroll
      for (int d = 0; d < 64; d++) a += qs[w][d] * Kt[lane][d];
      s = a * (1.f / 64.f);  // muP: 1/d_head
    }
    float mt = s;
#pragma unroll
    for (int off = 32; off; off >>= 1) mt = fmaxf(mt, __shfl_xor(mt, off));
    float mnew = fmaxf(m_i, mt);
    float alpha = (m_i == -INFINITY) ? 0.f : expf(m_i - mnew);
    float p = (tk <= tq) ? expf(s - mnew) : 0.f;
    float psum = p;
#pragma unroll
    for (int off = 32; off; off >>= 1) psum += __shfl_xor(psum, off);
    l_i = l_i * alpha + psum;
    ps[w][lane] = p;
    float pv = 0.f;
#pragma unroll
    for (int j = 0; j < 64; j++) pv += ps[w][j] * Vt[j][lane];
    acc = acc * alpha + pv;
    m_i = mnew;
  }
  y[rowbase + lane] = (bf16_t)(acc / l_i);
}

// ---------------------------------------------------------------- host
static inline void launch_gemm(const bf16_t* A, const void* W, size_t woffs,
                               const void* bias, size_t boff, const float* res,
                               bf16_t* outb, float* outf, void* outx,
                               const int* modep, int M, int N, int K,
                               int dogelu, hipStream_t s)
{
  dim3 g(N / 64, M / 64);
  gemm_bt<<<g, dim3(256), 0, s>>>(A, W, woffs, bias, boff, res, outb, outf,
                                  outx, modep, M, N, K, dogelu);
}

extern "C" void kernel_launch(void* const* d_in, const int* in_sizes, int n_in,
                              void* d_out, int out_size, void* d_ws, size_t ws_size,
                              hipStream_t stream)
{
  (void)in_sizes; (void)n_in; (void)out_size; (void)ws_size;
  const int* idx      = (const int*)d_in[0];
  const void* tok_emb = d_in[1];
  const void* pos_emb = d_in[2];
  const void* ln1_w   = d_in[3];
  const void* ln1_b   = d_in[4];
  const void* wq      = d_in[5];
  const void* wk      = d_in[6];
  const void* wv      = d_in[7];
  const void* wproj   = d_in[8];
  const void* ln2_w   = d_in[9];
  const void* ln2_b   = d_in[10];
  const void* fc1_w   = d_in[11];
  const void* fc1_b   = d_in[12];
  const void* fc2_w   = d_in[13];
  const void* fc2_b   = d_in[14];
  const void* lnf_w   = d_in[15];
  const void* lnf_b   = d_in[16];
  const void* head_w  = d_in[17];

  char* ws = (char*)d_ws;
  int*    modep = (int*)ws;                   // 4 B flag
  float*  x  = (float*)(ws + 256);            // 2048*1024 f32   = 8 MB
  bf16_t* h  = (bf16_t*)(ws + 8388864);       // 2048*1024 bf16  = 4 MB
  bf16_t* qb = (bf16_t*)(ws + 12583168);      // 4 MB
  bf16_t* kb = (bf16_t*)(ws + 16777472);      // 4 MB
  bf16_t* vb = (bf16_t*)(ws + 20971776);      // 4 MB
  bf16_t* yb = (bf16_t*)(ws + 25166080);      // 4 MB
  bf16_t* hf = (bf16_t*)(ws + 29360384);      // 2048*4096 bf16  = 16 MB

  detect_kernel<<<1, 256, 0, stream>>>((const unsigned short*)tok_emb, modep);
  embed_kernel<<<NTOK, 256, 0, stream>>>(idx, tok_emb, pos_emb, x, modep);

  for (int l = 0; l < L_; l++) {
    size_t wd = (size_t)l * D_ * D_;   // element offset into [L,D,D]
    size_t wf = (size_t)l * F_ * D_;   // element offset into [L,F,D] / [L,D,F]
    ln_kernel<<<NTOK, 256, 0, stream>>>(x, ln1_w, ln1_b, h, modep, l * D_);
    launch_gemm(h, wq, wd, nullptr, 0, nullptr, qb, nullptr, nullptr, modep,
                NTOK, D_, D_, 0, stream);
    launch_gemm(h, wk, wd, nullptr, 0, nullptr, kb, nullptr, nullptr, modep,
                NTOK, D_, D_, 0, stream);
    launch_gemm(h, wv, wd, nullptr, 0, nullptr, vb, nullptr, nullptr, modep,
                NTOK, D_, D_, 0, stream);
    attn_kernel<<<B_ * H_ * (T_ / 4), 256, 0, stream>>>(qb, kb, vb, yb);
    launch_gemm(yb, wproj, wd, nullptr, 0, x, nullptr, x, nullptr, modep,
                NTOK, D_, D_, 0, stream);
    ln_kernel<<<NTOK, 256, 0, stream>>>(x, ln2_w, ln2_b, h, modep, l * D_);
    launch_gemm(h, fc1_w, wf, fc1_b, (size_t)l * F_, nullptr, hf, nullptr,
                nullptr, modep, NTOK, F_, D_, 1, stream);
    launch_gemm(hf, fc2_w, wf, fc2_b, (size_t)l * D_, x, nullptr, x, nullptr,
                modep, NTOK, D_, F_, 0, stream);
  }

  ln_kernel<<<NTOK, 256, 0, stream>>>(x, lnf_w, lnf_b, h, modep, 0);
  launch_gemm(h, head_w, 0, nullptr, 0, nullptr, nullptr, nullptr, d_out,
              modep, NTOK, V_, D_, 0, stream);
}